// Round 6
// baseline (804.937 us; speedup 1.0000x reference)
//
#include <hip/hip_runtime.h>
#include <math.h>

#define NN 50000
#define NE 800000
#define MUL 32
#define CHUNK 16
#define SCANB 49   /* ceil(NN/1024) */

static __device__ __forceinline__ float sigmoidf_(float v) {
    return 1.0f / (1.0f + __expf(-v));
}

#define INV_SQRT_MUL   0.17677669529663687f   /* 1/sqrt(32) */
#define INV_SQRT_NEMB  0.35355339059327373f   /* 1/sqrt(8)  */
#define INV_SQRT_HID   0.35355339059327373f   /* 1/sqrt(8)  */
#define INV3C          0.5773502691896258f    /* 1/sqrt(3)  */
#define INV2C          0.7071067811865476f    /* 1/sqrt(2)  */
#define INV_NEIGH      0.25f                  /* 1/sqrt(16) */
#define INV_SQRT_2MUL  0.125f                 /* 1/sqrt(64) */
#define INV_SQRT_3MUL  0.10206207261596575f   /* 1/sqrt(96) */
#define NSC            0.0625f                /* 1/sqrt(32*8) */

// ---------------------------------------------------------------------------
// K1 (v4): block = 256 threads = 4 waves covering 64 nodes.
// Wave w handles part w: w=0 -> scalar path (W1_s/Wsc_s), w=1..3 -> vector
// component c=w-1 (W1_v/Wsc_v). Part is wave-uniform -> weight indices are
// loop-counter-only -> s_load scalarization (SGPR operands to v_fma).
// Outputs staged in LDS (stride 129: conflict-free) and stored coalesced.
// x layout: [0..31]=x_s[v], [32+u*3+c]=x_v[u][c]
// ---------------------------------------------------------------------------
__global__ __launch_bounds__(256) void k_node(
    const float* __restrict__ node_s, const float* __restrict__ node_v,
    const float* __restrict__ attrs,
    const float* __restrict__ W1_s, const float* __restrict__ W1_v,
    const float* __restrict__ Wsc_s, const float* __restrict__ Wsc_v,
    float* __restrict__ x, float* __restrict__ out)
{
    __shared__ float st[64 * 129];
    const int base = blockIdx.x * 64;
    const int t = threadIdx.x;
    const int l = t & 63;     // node within block
    const int w = t >> 6;     // part (wave-uniform)
    const int n = base + l;
    const bool act = (n < NN);

    float at[8];
    float in[32];
#pragma unroll
    for (int a = 0; a < 8; ++a) at[a] = 0.f;
#pragma unroll
    for (int u = 0; u < 32; ++u) in[u] = 0.f;
    if (act) {
        const float4* ap = (const float4*)(attrs + n * 8);
        float4 a0 = ap[0], a1 = ap[1];
        at[0] = a0.x; at[1] = a0.y; at[2] = a0.z; at[3] = a0.w;
        at[4] = a1.x; at[5] = a1.y; at[6] = a1.z; at[7] = a1.w;
        if (w == 0) {
            const float4* sp = (const float4*)(node_s + n * 32);
#pragma unroll
            for (int q = 0; q < 8; ++q) {
                float4 f = sp[q];
                in[4 * q] = f.x; in[4 * q + 1] = f.y;
                in[4 * q + 2] = f.z; in[4 * q + 3] = f.w;
            }
        } else {
            const int c = w - 1;
#pragma unroll
            for (int u = 0; u < 32; ++u) in[u] = node_v[n * 96 + 3 * u + c];
        }
    }

    const float* __restrict__ W1  = (w == 0) ? W1_s : W1_v;
    const float* __restrict__ Wsc = (w == 0) ? Wsc_s : Wsc_v;

    float xs[32], acc[32];
#pragma unroll
    for (int v = 0; v < 32; ++v) { xs[v] = 0.f; acc[v] = 0.f; }

    for (int u = 0; u < 32; ++u) {
        const float su = in[u];
        const float* w1r = &W1[u * 32];
#pragma unroll
        for (int v = 0; v < 32; ++v) xs[v] += su * w1r[v];
#pragma unroll
        for (int a = 0; a < 8; ++a) {
            const float p = su * at[a];
            const float* wr = &Wsc[(u * 8 + a) * 32];
#pragma unroll
            for (int v = 0; v < 32; ++v) acc[v] += p * wr[v];
        }
    }

    const int lim = (NN - base < 64 ? NN - base : 64) * 128;

    // ---- stage + coalesced store: x
    if (act) {
        if (w == 0) {
#pragma unroll
            for (int v = 0; v < 32; ++v) st[l * 129 + v] = xs[v] * INV_SQRT_MUL;
        } else {
            const int c = w - 1;
#pragma unroll
            for (int v = 0; v < 32; ++v) st[l * 129 + 32 + 3 * v + c] = xs[v] * INV_SQRT_MUL;
        }
    }
    __syncthreads();
#pragma unroll
    for (int r = 0; r < 32; ++r) {
        int fi = t + 256 * r;
        if (fi < lim) {
            int node = fi >> 7, ch = fi & 127;
            x[(size_t)base * 128 + fi] = st[node * 129 + ch];
        }
    }
    __syncthreads();

    // ---- stage + coalesced store: out (self-connection)
    if (act) {
        if (w == 0) {
#pragma unroll
            for (int v = 0; v < 32; ++v) st[l * 129 + v] = acc[v] * NSC;
        } else {
            const int c = w - 1;
#pragma unroll
            for (int v = 0; v < 32; ++v) st[l * 129 + 32 + 3 * v + c] = acc[v] * NSC;
        }
    }
    __syncthreads();
#pragma unroll
    for (int r = 0; r < 32; ++r) {
        int fi = t + 256 * r;
        if (fi < lim) {
            int node = fi >> 7, ch = fi & 127;
            out[(size_t)base * 128 + fi] = st[node * 129 + ch];
        }
    }
}

// ---------------------------------------------------------------------------
// K2: dst histogram
// ---------------------------------------------------------------------------
__global__ __launch_bounds__(256) void k_hist(
    const int* __restrict__ edge_dst, int* __restrict__ counts)
{
    int e = blockIdx.x * 256 + threadIdx.x;
    if (e >= NE) return;
    atomicAdd(&counts[edge_dst[e]], 1);
}

// ---------------------------------------------------------------------------
// K3a: per-block exclusive scan (1024 elems/block) + block sums
// ---------------------------------------------------------------------------
__global__ __launch_bounds__(1024) void k_scan_a(
    const int* __restrict__ counts, int* __restrict__ escan,
    int* __restrict__ bsum)
{
    __shared__ int sh[1024];
    const int t = threadIdx.x;
    const int i = blockIdx.x * 1024 + t;
    int v = (i < NN) ? counts[i] : 0;
    sh[t] = v;
    __syncthreads();
    for (int off = 1; off < 1024; off <<= 1) {
        int u = (t >= off) ? sh[t - off] : 0;
        __syncthreads();
        sh[t] += u;
        __syncthreads();
    }
    if (i < NN) escan[i] = sh[t] - v;
    if (t == 1023) bsum[blockIdx.x] = sh[1023];
}

// ---------------------------------------------------------------------------
// K3b: exclusive scan of the 49 block sums (one wave)
// ---------------------------------------------------------------------------
__global__ __launch_bounds__(64) void k_scan_b(int* __restrict__ bsum)
{
    const int t = threadIdx.x;
    int v = (t < SCANB) ? bsum[t] : 0;
    const int orig = v;
    for (int off = 1; off < 64; off <<= 1) {
        int u = __shfl_up(v, off, 64);
        if (t >= off) v += u;
    }
    if (t < SCANB) bsum[t] = v - orig;
}

// ---------------------------------------------------------------------------
// K3c: add-back -> offsets[N+1], cursor[N]
// ---------------------------------------------------------------------------
__global__ __launch_bounds__(1024) void k_scan_c(
    const int* __restrict__ escan, const int* __restrict__ bsum,
    int* __restrict__ offsets, int* __restrict__ cursor)
{
    const int i = blockIdx.x * 1024 + threadIdx.x;
    if (i == 0) offsets[NN] = NE;
    if (i < NN) {
        int o = bsum[blockIdx.x] + escan[i];
        offsets[i] = o;
        cursor[i] = o;
    }
}

// ---------------------------------------------------------------------------
// K4: pack — radial-MLP hidden h + 64B record at CSR position.
// record: [0]=src(bits) [1]=sh0 [2..4]=sh1 [5..12]=h [13..15]=pad
// ---------------------------------------------------------------------------
__global__ __launch_bounds__(256) void k_pack(
    const float* __restrict__ edge_emb, const float* __restrict__ edge_sh0,
    const float* __restrict__ edge_sh1,
    const int* __restrict__ edge_src, const int* __restrict__ edge_dst,
    const float* __restrict__ Wm1,
    int* __restrict__ cursor, float* __restrict__ epack)
{
    int e = blockIdx.x * 256 + threadIdx.x;
    if (e >= NE) return;
    const float4* p = (const float4*)(edge_emb + e * 8);
    float4 a = p[0], b = p[1];
    float emb[8] = {a.x, a.y, a.z, a.w, b.x, b.y, b.z, b.w};
    float h[8];
#pragma unroll
    for (int j = 0; j < 8; ++j) {
        float s = 0.f;
#pragma unroll
        for (int k = 0; k < 8; ++k) s += emb[k] * Wm1[k * 8 + j];
        s *= INV_SQRT_NEMB;
        h[j] = s * sigmoidf_(s);   // silu
    }
    float sh0 = edge_sh0[e];
    float sx = edge_sh1[3 * e], sy = edge_sh1[3 * e + 1], sz = edge_sh1[3 * e + 2];
    int src = edge_src[e];
    int pos = atomicAdd(&cursor[edge_dst[e]], 1);
    float4* op = (float4*)(epack + (size_t)pos * 16);
    op[0] = make_float4(__int_as_float(src), sh0, sx, sy);
    op[1] = make_float4(sz, h[0], h[1], h[2]);
    op[2] = make_float4(h[3], h[4], h[5], h[6]);
    op[3] = make_float4(h[7], 0.f, 0.f, 0.f);
}

// ---------------------------------------------------------------------------
// K5: one wave per node. Lane-local decomposition: lane = (u = L&31,
// role = L>>5). Role 0 accumulates p1[u],p2[u],p3[u][*]; role 1 p4[u][*],
// p5[u][*]. Per-edge data is lane-private -> NO per-edge barriers.
// ---------------------------------------------------------------------------
__global__ __launch_bounds__(64) void k_gather(
    const float* __restrict__ x, const float* __restrict__ epack,
    const float* __restrict__ Wm2, const float* __restrict__ W2_s,
    const float* __restrict__ W2_v,
    const int* __restrict__ offsets, float* __restrict__ out)
{
    __shared__ float meta[CHUNK * 16];
    __shared__ float msg[352];
    const int n = blockIdx.x;
    const int L = threadIdx.x;
    const int u = L & 31;
    const int role = L >> 5;

    // Wm2 columns for this lane's paths: role0 -> {0,1,2}, role1 -> {3,4}
    float wc[3][8];
#pragma unroll
    for (int p = 0; p < 3; ++p) {
        int m = (role == 0 ? p : 3 + p) * 32 + u;
        if (m > 159) m = u;   // role1 third slot unused; keep in-bounds
#pragma unroll
        for (int q = 0; q < 8; ++q) wc[p][q] = Wm2[q * 160 + m];
    }

    float a0 = 0.f, a1 = 0.f;
    float b0 = 0.f, b1 = 0.f, b2 = 0.f;
    float c0 = 0.f, c1 = 0.f, c2 = 0.f;

    const int beg = offsets[n];
    const int end = offsets[n + 1];

    for (int base = beg; base < end; base += CHUNK) {
        const int cnt = min(CHUNK, end - base);
        {
            int ee = L >> 2;
            if (ee < cnt) {
                float4 v = ((const float4*)epack)[(size_t)(base + ee) * 4 + (L & 3)];
                *(float4*)&meta[ee * 16 + 4 * (L & 3)] = v;
            }
        }
        __syncthreads();

        float ls, lv0, lv1, lv2;
        {
            const float* xr = x + (size_t)__float_as_int(meta[0]) * 128;
            ls  = xr[u];
            lv0 = xr[32 + 3 * u]; lv1 = xr[33 + 3 * u]; lv2 = xr[34 + 3 * u];
        }
        for (int jj = 0; jj < cnt; ++jj) {
            float ns = 0.f, nv0 = 0.f, nv1 = 0.f, nv2 = 0.f;
            if (jj + 1 < cnt) {
                const float* xr = x + (size_t)__float_as_int(meta[(jj + 1) * 16]) * 128;
                ns  = xr[u];
                nv0 = xr[32 + 3 * u]; nv1 = xr[33 + 3 * u]; nv2 = xr[34 + 3 * u];
            }
            const float* mp = &meta[jj * 16];
            const float sh0 = mp[1], sx = mp[2], sy = mp[3], sz = mp[4];
            float w0 = 0.f, w1 = 0.f, w2 = 0.f;
#pragma unroll
            for (int q = 0; q < 8; ++q) {
                float hq = mp[5 + q];
                w0 += hq * wc[0][q];
                w1 += hq * wc[1][q];
                w2 += hq * wc[2][q];
            }
            w0 *= INV_SQRT_HID; w1 *= INV_SQRT_HID; w2 *= INV_SQRT_HID;
            if (role == 0) {
                a0 += w0 * ls * sh0;
                float dot = lv0 * sx + lv1 * sy + lv2 * sz;
                a1 += w1 * dot;
                float t = w2 * ls;
                b0 += t * sx; b1 += t * sy; b2 += t * sz;
            } else {
                float t4 = w0 * sh0;
                b0 += t4 * lv0; b1 += t4 * lv1; b2 += t4 * lv2;
                float cx = lv1 * sz - lv2 * sy;
                float cy = lv2 * sx - lv0 * sz;
                float cz = lv0 * sy - lv1 * sx;
                c0 += w1 * cx; c1 += w1 * cy; c2 += w1 * cz;
            }
            ls = ns; lv0 = nv0; lv1 = nv1; lv2 = nv2;
        }
        __syncthreads();
    }

    // assemble msg[352]: [0..31]=p1, [32..63]=p2, [64+uu*3+c] uu=path*32+u
    if (role == 0) {
        msg[u]      = a0 * INV_NEIGH;
        msg[32 + u] = a1 * (INV3C * INV_NEIGH);
        int vb = 64 + u * 3;
        msg[vb]     = b0 * INV_NEIGH;
        msg[vb + 1] = b1 * INV_NEIGH;
        msg[vb + 2] = b2 * INV_NEIGH;
    } else {
        int vb4 = 64 + (32 + u) * 3;
        msg[vb4]     = b0 * INV_NEIGH;
        msg[vb4 + 1] = b1 * INV_NEIGH;
        msg[vb4 + 2] = b2 * INV_NEIGH;
        int vb5 = 64 + (64 + u) * 3;
        float f = INV2C * INV_NEIGH;
        msg[vb5]     = c0 * f;
        msg[vb5 + 1] = c1 * f;
        msg[vb5 + 2] = c2 * f;
    }
    __syncthreads();

    // fold linear_2, add to self-connection already in out
#pragma unroll
    for (int oo = 0; oo < 2; ++oo) {
        int o = oo * 64 + L;
        float r;
        if (o < 32) {
            float s = 0.f;
#pragma unroll
            for (int uu = 0; uu < 64; ++uu) s += msg[uu] * W2_s[uu * 32 + o];
            r = s * INV_SQRT_2MUL;
        } else {
            int q = o - 32;
            int vch = q / 3, c = q - 3 * vch;
            float s = 0.f;
#pragma unroll
            for (int uu = 0; uu < 96; ++uu) s += msg[64 + uu * 3 + c] * W2_v[uu * 32 + vch];
            r = s * INV_SQRT_3MUL;
        }
        out[128 * n + o] += r;
    }
}

// ---------------------------------------------------------------------------
extern "C" void kernel_launch(void* const* d_in, const int* in_sizes, int n_in,
                              void* d_out, int out_size, void* d_ws, size_t ws_size,
                              hipStream_t stream) {
    const float* node_s   = (const float*)d_in[0];
    const float* node_v   = (const float*)d_in[1];
    const float* attrs    = (const float*)d_in[2];
    const float* edge_emb = (const float*)d_in[3];
    const float* edge_sh0 = (const float*)d_in[4];
    const float* edge_sh1 = (const float*)d_in[5];
    const float* W1_s     = (const float*)d_in[6];
    const float* W1_v     = (const float*)d_in[7];
    const float* Wm1      = (const float*)d_in[8];
    const float* Wm2      = (const float*)d_in[9];
    const float* W2_s     = (const float*)d_in[10];
    const float* W2_v     = (const float*)d_in[11];
    const float* Wsc_s    = (const float*)d_in[12];
    const float* Wsc_v    = (const float*)d_in[13];
    const int*   edge_src = (const int*)d_in[14];
    const int*   edge_dst = (const int*)d_in[15];
    float* out = (float*)d_out;

    // workspace layout
    float* x     = (float*)d_ws;                     // N*128
    float* epack = x + (size_t)NN * 128;             // E*16
    int*   counts  = (int*)(epack + (size_t)NE * 16);// N
    int*   offsets = counts + NN;                    // N+1
    int*   cursor  = offsets + NN + 1;               // N
    int*   escan   = cursor + NN;                    // N
    int*   bsum    = escan + NN;                     // SCANB

    hipMemsetAsync(counts, 0, NN * sizeof(int), stream);

    k_node<<<(NN + 63) / 64, 256, 0, stream>>>(node_s, node_v, attrs,
                                               W1_s, W1_v, Wsc_s, Wsc_v,
                                               x, out);
    k_hist<<<(NE + 255) / 256, 256, 0, stream>>>(edge_dst, counts);
    k_scan_a<<<SCANB, 1024, 0, stream>>>(counts, escan, bsum);
    k_scan_b<<<1, 64, 0, stream>>>(bsum);
    k_scan_c<<<SCANB, 1024, 0, stream>>>(escan, bsum, offsets, cursor);
    k_pack<<<(NE + 255) / 256, 256, 0, stream>>>(edge_emb, edge_sh0, edge_sh1,
                                                 edge_src, edge_dst, Wm1,
                                                 cursor, epack);
    k_gather<<<NN, 64, 0, stream>>>(x, epack, Wm2, W2_s, W2_v, offsets, out);
}

// Round 7
// 499.042 us; speedup vs baseline: 1.6130x; 1.6130x over previous
//
#include <hip/hip_runtime.h>
#include <math.h>

#define NN 50000
#define NE 800000
#define MUL 32
#define CHUNK 16
#define SCANB 49   /* ceil(NN/1024) */

static __device__ __forceinline__ float sigmoidf_(float v) {
    return 1.0f / (1.0f + __expf(-v));
}

#define INV_SQRT_MUL   0.17677669529663687f   /* 1/sqrt(32) */
#define INV_SQRT_NEMB  0.35355339059327373f   /* 1/sqrt(8)  */
#define INV_SQRT_HID   0.35355339059327373f   /* 1/sqrt(8)  */
#define INV3C          0.5773502691896258f    /* 1/sqrt(3)  */
#define INV2C          0.7071067811865476f    /* 1/sqrt(2)  */
#define INV_NEIGH      0.25f                  /* 1/sqrt(16) */
#define INV_SQRT_2MUL  0.125f                 /* 1/sqrt(64) */
#define INV_SQRT_3MUL  0.10206207261596575f   /* 1/sqrt(96) */
#define NSC            0.0625f                /* 1/sqrt(32*8) */

// ---------------------------------------------------------------------------
// K1 (v5 = proven R4 structure x2 nodes/block): 256 threads = two 128-thread
// halves, each handling one node. Both halves read the same weight addresses
// in the same order -> second half served by L1. gs/gv = per-node
// attr-contracted weight tables in LDS; folds and stores as in R4
// (per-thread stores at x[n*128+t] are coalesced across the half).
// x layout: [0..31]=x_s[v], [32+u*3+c]=x_v[u][c]
// ---------------------------------------------------------------------------
__global__ __launch_bounds__(256) void k_node(
    const float* __restrict__ node_s, const float* __restrict__ node_v,
    const float* __restrict__ attrs,
    const float* __restrict__ W1_s, const float* __restrict__ W1_v,
    const float* __restrict__ Wsc_s, const float* __restrict__ Wsc_v,
    float* __restrict__ x, float* __restrict__ out)
{
    __shared__ float nd[2][136];
    __shared__ float gs[2][1024];
    __shared__ float gv[2][1024];
    const int t  = threadIdx.x;
    const int h  = t >> 7;       // which node of the pair
    const int tl = t & 127;      // thread within half
    const int n  = blockIdx.x * 2 + h;   // NN even, grid=NN/2 -> always valid

    if (tl < 32) nd[h][tl] = node_s[n * 32 + tl];
    else         nd[h][tl] = node_v[n * 96 + (tl - 32)];
    if (tl < 8)  nd[h][128 + tl] = attrs[n * 8 + tl];
    __syncthreads();

    float at[8];
#pragma unroll
    for (int a = 0; a < 8; ++a) at[a] = nd[h][128 + a];

#pragma unroll
    for (int r = 0; r < 8; ++r) {
        int idx = tl + 128 * r;
        int u = idx >> 5, vch = idx & 31;
        float as = 0.f, av = 0.f;
#pragma unroll
        for (int a = 0; a < 8; ++a) {
            as += at[a] * Wsc_s[(u * 8 + a) * 32 + vch];
            av += at[a] * Wsc_v[(u * 8 + a) * 32 + vch];
        }
        gs[h][idx] = as;
        gv[h][idx] = av;
    }
    __syncthreads();

    float xa = 0.f, sc = 0.f;
    if (tl < 32) {
#pragma unroll
        for (int u = 0; u < 32; ++u) {
            xa += nd[h][u] * W1_s[u * 32 + tl];
            sc += nd[h][u] * gs[h][(u << 5) + tl];
        }
    } else {
        int q = tl - 32;
        int vch = q / 3, c = q - 3 * vch;
#pragma unroll
        for (int u = 0; u < 32; ++u) {
            float vv = nd[h][32 + u * 3 + c];
            xa += vv * W1_v[u * 32 + vch];
            sc += vv * gv[h][(u << 5) + vch];
        }
    }
    x[n * 128 + tl]   = xa * INV_SQRT_MUL;
    out[n * 128 + tl] = sc * NSC;   // message part added later by k_gather
}

// ---------------------------------------------------------------------------
// K2: dst histogram
// ---------------------------------------------------------------------------
__global__ __launch_bounds__(256) void k_hist(
    const int* __restrict__ edge_dst, int* __restrict__ counts)
{
    int e = blockIdx.x * 256 + threadIdx.x;
    if (e >= NE) return;
    atomicAdd(&counts[edge_dst[e]], 1);
}

// ---------------------------------------------------------------------------
// K3a: per-block exclusive scan (1024 elems/block) + block sums
// ---------------------------------------------------------------------------
__global__ __launch_bounds__(1024) void k_scan_a(
    const int* __restrict__ counts, int* __restrict__ escan,
    int* __restrict__ bsum)
{
    __shared__ int sh[1024];
    const int t = threadIdx.x;
    const int i = blockIdx.x * 1024 + t;
    int v = (i < NN) ? counts[i] : 0;
    sh[t] = v;
    __syncthreads();
    for (int off = 1; off < 1024; off <<= 1) {
        int u = (t >= off) ? sh[t - off] : 0;
        __syncthreads();
        sh[t] += u;
        __syncthreads();
    }
    if (i < NN) escan[i] = sh[t] - v;
    if (t == 1023) bsum[blockIdx.x] = sh[1023];
}

// ---------------------------------------------------------------------------
// K3b: exclusive scan of the 49 block sums (one wave)
// ---------------------------------------------------------------------------
__global__ __launch_bounds__(64) void k_scan_b(int* __restrict__ bsum)
{
    const int t = threadIdx.x;
    int v = (t < SCANB) ? bsum[t] : 0;
    const int orig = v;
    for (int off = 1; off < 64; off <<= 1) {
        int u = __shfl_up(v, off, 64);
        if (t >= off) v += u;
    }
    if (t < SCANB) bsum[t] = v - orig;
}

// ---------------------------------------------------------------------------
// K3c: add-back -> offsets[N+1], cursor[N]
// ---------------------------------------------------------------------------
__global__ __launch_bounds__(1024) void k_scan_c(
    const int* __restrict__ escan, const int* __restrict__ bsum,
    int* __restrict__ offsets, int* __restrict__ cursor)
{
    const int i = blockIdx.x * 1024 + threadIdx.x;
    if (i == 0) offsets[NN] = NE;
    if (i < NN) {
        int o = bsum[blockIdx.x] + escan[i];
        offsets[i] = o;
        cursor[i] = o;
    }
}

// ---------------------------------------------------------------------------
// K4: pack — radial-MLP hidden h + 64B record at CSR position.
// record: [0]=src(bits) [1]=sh0 [2..4]=sh1 [5..12]=h [13..15]=pad
// ---------------------------------------------------------------------------
__global__ __launch_bounds__(256) void k_pack(
    const float* __restrict__ edge_emb, const float* __restrict__ edge_sh0,
    const float* __restrict__ edge_sh1,
    const int* __restrict__ edge_src, const int* __restrict__ edge_dst,
    const float* __restrict__ Wm1,
    int* __restrict__ cursor, float* __restrict__ epack)
{
    int e = blockIdx.x * 256 + threadIdx.x;
    if (e >= NE) return;
    const float4* p = (const float4*)(edge_emb + e * 8);
    float4 a = p[0], b = p[1];
    float emb[8] = {a.x, a.y, a.z, a.w, b.x, b.y, b.z, b.w};
    float h[8];
#pragma unroll
    for (int j = 0; j < 8; ++j) {
        float s = 0.f;
#pragma unroll
        for (int k = 0; k < 8; ++k) s += emb[k] * Wm1[k * 8 + j];
        s *= INV_SQRT_NEMB;
        h[j] = s * sigmoidf_(s);   // silu
    }
    float sh0 = edge_sh0[e];
    float sx = edge_sh1[3 * e], sy = edge_sh1[3 * e + 1], sz = edge_sh1[3 * e + 2];
    int src = edge_src[e];
    int pos = atomicAdd(&cursor[edge_dst[e]], 1);
    float4* op = (float4*)(epack + (size_t)pos * 16);
    op[0] = make_float4(__int_as_float(src), sh0, sx, sy);
    op[1] = make_float4(sz, h[0], h[1], h[2]);
    op[2] = make_float4(h[3], h[4], h[5], h[6]);
    op[3] = make_float4(h[7], 0.f, 0.f, 0.f);
}

// ---------------------------------------------------------------------------
// K5: one wave per node. Lane-local decomposition: lane = (u = L&31,
// role = L>>5). Role 0 accumulates p1[u],p2[u],p3[u][*]; role 1 p4[u][*],
// p5[u][*]. Per-edge data is lane-private -> NO per-edge barriers.
// ---------------------------------------------------------------------------
__global__ __launch_bounds__(64) void k_gather(
    const float* __restrict__ x, const float* __restrict__ epack,
    const float* __restrict__ Wm2, const float* __restrict__ W2_s,
    const float* __restrict__ W2_v,
    const int* __restrict__ offsets, float* __restrict__ out)
{
    __shared__ float meta[CHUNK * 16];
    __shared__ float msg[352];
    const int n = blockIdx.x;
    const int L = threadIdx.x;
    const int u = L & 31;
    const int role = L >> 5;

    // Wm2 columns for this lane's paths: role0 -> {0,1,2}, role1 -> {3,4}
    float wc[3][8];
#pragma unroll
    for (int p = 0; p < 3; ++p) {
        int m = (role == 0 ? p : 3 + p) * 32 + u;
        if (m > 159) m = u;   // role1 third slot unused; keep in-bounds
#pragma unroll
        for (int q = 0; q < 8; ++q) wc[p][q] = Wm2[q * 160 + m];
    }

    float a0 = 0.f, a1 = 0.f;
    float b0 = 0.f, b1 = 0.f, b2 = 0.f;
    float c0 = 0.f, c1 = 0.f, c2 = 0.f;

    const int beg = offsets[n];
    const int end = offsets[n + 1];

    for (int base = beg; base < end; base += CHUNK) {
        const int cnt = min(CHUNK, end - base);
        {
            int ee = L >> 2;
            if (ee < cnt) {
                float4 v = ((const float4*)epack)[(size_t)(base + ee) * 4 + (L & 3)];
                *(float4*)&meta[ee * 16 + 4 * (L & 3)] = v;
            }
        }
        __syncthreads();

        float ls, lv0, lv1, lv2;
        {
            const float* xr = x + (size_t)__float_as_int(meta[0]) * 128;
            ls  = xr[u];
            lv0 = xr[32 + 3 * u]; lv1 = xr[33 + 3 * u]; lv2 = xr[34 + 3 * u];
        }
        for (int jj = 0; jj < cnt; ++jj) {
            float ns = 0.f, nv0 = 0.f, nv1 = 0.f, nv2 = 0.f;
            if (jj + 1 < cnt) {
                const float* xr = x + (size_t)__float_as_int(meta[(jj + 1) * 16]) * 128;
                ns  = xr[u];
                nv0 = xr[32 + 3 * u]; nv1 = xr[33 + 3 * u]; nv2 = xr[34 + 3 * u];
            }
            const float* mp = &meta[jj * 16];
            const float sh0 = mp[1], sx = mp[2], sy = mp[3], sz = mp[4];
            float w0 = 0.f, w1 = 0.f, w2 = 0.f;
#pragma unroll
            for (int q = 0; q < 8; ++q) {
                float hq = mp[5 + q];
                w0 += hq * wc[0][q];
                w1 += hq * wc[1][q];
                w2 += hq * wc[2][q];
            }
            w0 *= INV_SQRT_HID; w1 *= INV_SQRT_HID; w2 *= INV_SQRT_HID;
            if (role == 0) {
                a0 += w0 * ls * sh0;
                float dot = lv0 * sx + lv1 * sy + lv2 * sz;
                a1 += w1 * dot;
                float t = w2 * ls;
                b0 += t * sx; b1 += t * sy; b2 += t * sz;
            } else {
                float t4 = w0 * sh0;
                b0 += t4 * lv0; b1 += t4 * lv1; b2 += t4 * lv2;
                float cx = lv1 * sz - lv2 * sy;
                float cy = lv2 * sx - lv0 * sz;
                float cz = lv0 * sy - lv1 * sx;
                c0 += w1 * cx; c1 += w1 * cy; c2 += w1 * cz;
            }
            ls = ns; lv0 = nv0; lv1 = nv1; lv2 = nv2;
        }
        __syncthreads();
    }

    // assemble msg[352]: [0..31]=p1, [32..63]=p2, [64+uu*3+c] uu=path*32+u
    if (role == 0) {
        msg[u]      = a0 * INV_NEIGH;
        msg[32 + u] = a1 * (INV3C * INV_NEIGH);
        int vb = 64 + u * 3;
        msg[vb]     = b0 * INV_NEIGH;
        msg[vb + 1] = b1 * INV_NEIGH;
        msg[vb + 2] = b2 * INV_NEIGH;
    } else {
        int vb4 = 64 + (32 + u) * 3;
        msg[vb4]     = b0 * INV_NEIGH;
        msg[vb4 + 1] = b1 * INV_NEIGH;
        msg[vb4 + 2] = b2 * INV_NEIGH;
        int vb5 = 64 + (64 + u) * 3;
        float f = INV2C * INV_NEIGH;
        msg[vb5]     = c0 * f;
        msg[vb5 + 1] = c1 * f;
        msg[vb5 + 2] = c2 * f;
    }
    __syncthreads();

    // fold linear_2, add to self-connection already in out
#pragma unroll
    for (int oo = 0; oo < 2; ++oo) {
        int o = oo * 64 + L;
        float r;
        if (o < 32) {
            float s = 0.f;
#pragma unroll
            for (int uu = 0; uu < 64; ++uu) s += msg[uu] * W2_s[uu * 32 + o];
            r = s * INV_SQRT_2MUL;
        } else {
            int q = o - 32;
            int vch = q / 3, c = q - 3 * vch;
            float s = 0.f;
#pragma unroll
            for (int uu = 0; uu < 96; ++uu) s += msg[64 + uu * 3 + c] * W2_v[uu * 32 + vch];
            r = s * INV_SQRT_3MUL;
        }
        out[128 * n + o] += r;
    }
}

// ---------------------------------------------------------------------------
extern "C" void kernel_launch(void* const* d_in, const int* in_sizes, int n_in,
                              void* d_out, int out_size, void* d_ws, size_t ws_size,
                              hipStream_t stream) {
    const float* node_s   = (const float*)d_in[0];
    const float* node_v   = (const float*)d_in[1];
    const float* attrs    = (const float*)d_in[2];
    const float* edge_emb = (const float*)d_in[3];
    const float* edge_sh0 = (const float*)d_in[4];
    const float* edge_sh1 = (const float*)d_in[5];
    const float* W1_s     = (const float*)d_in[6];
    const float* W1_v     = (const float*)d_in[7];
    const float* Wm1      = (const float*)d_in[8];
    const float* Wm2      = (const float*)d_in[9];
    const float* W2_s     = (const float*)d_in[10];
    const float* W2_v     = (const float*)d_in[11];
    const float* Wsc_s    = (const float*)d_in[12];
    const float* Wsc_v    = (const float*)d_in[13];
    const int*   edge_src = (const int*)d_in[14];
    const int*   edge_dst = (const int*)d_in[15];
    float* out = (float*)d_out;

    // workspace layout
    float* x     = (float*)d_ws;                     // N*128
    float* epack = x + (size_t)NN * 128;             // E*16
    int*   counts  = (int*)(epack + (size_t)NE * 16);// N
    int*   offsets = counts + NN;                    // N+1
    int*   cursor  = offsets + NN + 1;               // N
    int*   escan   = cursor + NN;                    // N
    int*   bsum    = escan + NN;                     // SCANB

    hipMemsetAsync(counts, 0, NN * sizeof(int), stream);

    k_node<<<NN / 2, 256, 0, stream>>>(node_s, node_v, attrs,
                                       W1_s, W1_v, Wsc_s, Wsc_v, x, out);
    k_hist<<<(NE + 255) / 256, 256, 0, stream>>>(edge_dst, counts);
    k_scan_a<<<SCANB, 1024, 0, stream>>>(counts, escan, bsum);
    k_scan_b<<<1, 64, 0, stream>>>(bsum);
    k_scan_c<<<SCANB, 1024, 0, stream>>>(escan, bsum, offsets, cursor);
    k_pack<<<(NE + 255) / 256, 256, 0, stream>>>(edge_emb, edge_sh0, edge_sh1,
                                                 edge_src, edge_dst, Wm1,
                                                 cursor, epack);
    k_gather<<<NN, 64, 0, stream>>>(x, epack, Wm2, W2_s, W2_v, offsets, out);
}